// Round 14
// baseline (341.032 us; speedup 1.0000x reference)
//
#include <hip/hip_runtime.h>
#include <hip/hip_fp16.h>

// GCN 2-layer collapsed (x is [N,1] => layer 1 is rank-1):
//   out[c] = dis[c]*(sum_{r->c} gp[r] + gp[c]) + b2,  gp[r] = (relu(W1*a[r]+b1)@W2)*dis[r]
//   a[r]   = dis[r]*(sum_{r'->r} p[r'] + p[r]),       p[r']=x[r']*dis[r'], dis=1/sqrt(deg+1)
//
// Empirical laws (R1-R13): global atomics 20G/s; scattered 4B global stores ~10x
// write-through; aggregation passes are LDS-ATOMIC-PIPE bound (~55us per lane-op/edge
// + ~30us gather surcharge) -- invariant to occupancy/sorting/caching/preload/ILP.
// R13 (u64-packed o-pass, 1 op/edge) dropped total 422->325; k_part now top (100us),
// ~70% of its LDS traffic is the 9-level binary search recovering the chunk key.
// R14: store key at placement (u16 s_key) + prefold s_off = gbase - s_start ->
// output loop is 3 LDS reads. PTILE 4096 keeps LDS at 32KB (5 blocks/CU).

#define KMAX  512
#define PTPB  512
#define PU    8
#define PTILE (PTPB * PU)    // 4096

#define CSH   10
#define CN    1024
#define ATPB  256

#define FXS   131072.0f          // 2^17
#define FXSI  (1.0f / 131072.0f)
#define FXB   (1u << 21)

// ---------- zero ----------
__global__ void k_zero(int* __restrict__ a, int m) {
    int i = blockIdx.x * blockDim.x + threadIdx.x;
    if (i < m) a[i] = 0;
}

// ---------- chunk histogram ----------
__global__ void k_count(const int* __restrict__ col, int ne, int ne4,
                        int* __restrict__ totals, int K) {
    __shared__ int cnt[KMAX];
    for (int i = threadIdx.x; i < K; i += blockDim.x) cnt[i] = 0;
    __syncthreads();
    int tid = blockIdx.x * blockDim.x + threadIdx.x;
    int stride = gridDim.x * blockDim.x;
    const int4* col4 = (const int4*)col;
    for (int e = tid; e < ne4; e += stride) {
        int4 cc = col4[e];
        atomicAdd(&cnt[cc.x >> CSH], 1);
        atomicAdd(&cnt[cc.y >> CSH], 1);
        atomicAdd(&cnt[cc.z >> CSH], 1);
        atomicAdd(&cnt[cc.w >> CSH], 1);
    }
    for (int e = (ne4 << 2) + tid; e < ne; e += stride)
        atomicAdd(&cnt[col[e] >> CSH], 1);
    __syncthreads();
    for (int i = threadIdx.x; i < K; i += blockDim.x)
        if (cnt[i]) atomicAdd(&totals[i], cnt[i]);
}

// ---------- serial scan (K<=512) ----------
__global__ void k_scan(const int* __restrict__ totals, int* __restrict__ bbase,
                       int* __restrict__ cursor, int K) {
    if (threadIdx.x == 0 && blockIdx.x == 0) {
        int run = 0;
        for (int k = 0; k < K; ++k) { bbase[k] = run; cursor[k] = run; run += totals[k]; }
        bbase[K] = run;
    }
}

// ---------- tile-local LDS counting sort partition (key = col>>CSH) ----------
// R14: s_key (u16) stored at placement; output = s_off[key] + i (no binary search)
__global__ __launch_bounds__(PTPB) void k_part(
    const int* __restrict__ row, const int* __restrict__ col, int ne,
    int* __restrict__ cursor, int* __restrict__ packed, int K)
{
    __shared__ int s_cnt[KMAX];
    __shared__ int s_start[KMAX + 1];
    __shared__ int s_cur[KMAX];
    __shared__ int s_off[KMAX];
    __shared__ int s_sorted[PTILE];             // 16 KB
    __shared__ unsigned short s_key[PTILE];     // 8 KB

    int tb = blockIdx.x * PTILE;
    int tilecount = ne - tb;
    if (tilecount > PTILE) tilecount = PTILE;

    for (int i = threadIdx.x; i < K; i += PTPB) s_cnt[i] = 0;
    __syncthreads();

    int r[PU], c[PU];
    const int4* row4 = (const int4*)row;
    const int4* col4 = (const int4*)col;
    int tb4 = tb >> 2;
#pragma unroll
    for (int j = 0; j < PU / 4; ++j) {
        int g4 = tb4 + j * PTPB + threadIdx.x;
        int e = g4 << 2;
        if (e + 3 < ne) {
            int4 rr = row4[g4];
            int4 cc = col4[g4];
            r[4 * j + 0] = rr.x; r[4 * j + 1] = rr.y; r[4 * j + 2] = rr.z; r[4 * j + 3] = rr.w;
            c[4 * j + 0] = cc.x; c[4 * j + 1] = cc.y; c[4 * j + 2] = cc.z; c[4 * j + 3] = cc.w;
        } else {
#pragma unroll
            for (int q = 0; q < 4; ++q) {
                int e2 = e + q;
                if (e2 < ne) { r[4 * j + q] = row[e2]; c[4 * j + q] = col[e2]; }
                else { r[4 * j + q] = 0; c[4 * j + q] = -1; }
            }
        }
    }
#pragma unroll
    for (int j = 0; j < PU; ++j)
        if (c[j] >= 0) atomicAdd(&s_cnt[c[j] >> CSH], 1);
    __syncthreads();

    if (threadIdx.x == 0) {
        int run = 0;
        for (int k = 0; k < K; ++k) { s_start[k] = run; run += s_cnt[k]; }
        s_start[K] = run;
    }
    __syncthreads();
    if ((int)threadIdx.x < K) {
        int n0 = s_cnt[threadIdx.x];
        int gbase = n0 ? atomicAdd(&cursor[threadIdx.x], n0) : 0;
        s_off[threadIdx.x] = gbase - s_start[threadIdx.x];
        s_cur[threadIdx.x] = s_start[threadIdx.x];
    }
    __syncthreads();

#pragma unroll
    for (int j = 0; j < PU; ++j) {
        if (c[j] >= 0) {
            int ck = c[j] >> CSH;
            int pos = atomicAdd(&s_cur[ck], 1);
            s_sorted[pos] = (r[j] << CSH) | (c[j] & (CN - 1));
            s_key[pos] = (unsigned short)ck;
        }
    }
    __syncthreads();

    for (int i = threadIdx.x; i < tilecount; i += PTPB) {
        int key = s_key[i];
        packed[s_off[key] + i] = s_sorted[i];
    }
}

// ---------- fused degree -> dis, p, degArr (one block per chunk) ----------
__global__ __launch_bounds__(ATPB) void k_deg1(
    const float* __restrict__ x, const int* __restrict__ packed,
    const int* __restrict__ bbase, float* __restrict__ dis, float* __restrict__ p,
    int* __restrict__ degArr, int n)
{
    __shared__ int cnt[CN];
    int k = blockIdx.x;
    int node0 = k << CSH;
    int nn = min(CN, n - node0);
    for (int i = threadIdx.x; i < CN; i += ATPB) cnt[i] = 0;
    __syncthreads();
    int e0 = bbase[k], e1 = bbase[k + 1];
    int a0 = min((e0 + 3) & ~3, e1);
    int nb = (e1 - a0) >> 3;   // 8-edge groups
    for (int e = e0 + (int)threadIdx.x; e < a0; e += ATPB)
        atomicAdd(&cnt[packed[e] & (CN - 1)], 1);
    const int4* pk4 = (const int4*)packed;
    int b4 = a0 >> 2;
    for (int g = threadIdx.x; g < nb; g += ATPB) {
        int4 v0 = pk4[b4 + 2 * g];
        int4 v1 = pk4[b4 + 2 * g + 1];
        atomicAdd(&cnt[v0.x & (CN - 1)], 1);
        atomicAdd(&cnt[v0.y & (CN - 1)], 1);
        atomicAdd(&cnt[v0.z & (CN - 1)], 1);
        atomicAdd(&cnt[v0.w & (CN - 1)], 1);
        atomicAdd(&cnt[v1.x & (CN - 1)], 1);
        atomicAdd(&cnt[v1.y & (CN - 1)], 1);
        atomicAdd(&cnt[v1.z & (CN - 1)], 1);
        atomicAdd(&cnt[v1.w & (CN - 1)], 1);
    }
    for (int e = a0 + 8 * nb + (int)threadIdx.x; e < e1; e += ATPB)
        atomicAdd(&cnt[packed[e] & (CN - 1)], 1);
    __syncthreads();
    for (int i = threadIdx.x; i < nn; i += ATPB) {
        int c0 = cnt[i];
        float ds = rsqrtf(1.0f + (float)c0);
        dis[node0 + i] = ds;
        p[node0 + i] = x[node0 + i] * ds;
        degArr[node0 + i] = c0;
    }
}

// ---------- fused scalar aggregation + MLP -> gp (__half2) ----------
__global__ __launch_bounds__(ATPB) void k_s1(
    const int* __restrict__ packed, const int* __restrict__ bbase,
    const float* __restrict__ p, const float* __restrict__ dis,
    const float* __restrict__ W1, const float* __restrict__ b1,
    const float* __restrict__ W2, __half2* __restrict__ gp, int n)
{
    __shared__ float sv[CN];
    int k = blockIdx.x;
    int node0 = k << CSH;
    int nn = min(CN, n - node0);
    for (int i = threadIdx.x; i < CN; i += ATPB) sv[i] = 0.0f;
    __syncthreads();
    int e0 = bbase[k], e1 = bbase[k + 1];
    int a0 = min((e0 + 3) & ~3, e1);
    int nb = (e1 - a0) >> 3;
    for (int e = e0 + (int)threadIdx.x; e < a0; e += ATPB) {
        int v = packed[e];
        atomicAdd(&sv[v & (CN - 1)], p[((unsigned)v) >> CSH]);
    }
    const int4* pk4 = (const int4*)packed;
    int b4 = a0 >> 2;
    for (int g = threadIdx.x; g < nb; g += ATPB) {
        int4 v0 = pk4[b4 + 2 * g];
        int4 v1 = pk4[b4 + 2 * g + 1];
        float p0 = p[((unsigned)v0.x) >> CSH];
        float p1 = p[((unsigned)v0.y) >> CSH];
        float p2 = p[((unsigned)v0.z) >> CSH];
        float p3 = p[((unsigned)v0.w) >> CSH];
        float p4 = p[((unsigned)v1.x) >> CSH];
        float p5 = p[((unsigned)v1.y) >> CSH];
        float p6 = p[((unsigned)v1.z) >> CSH];
        float p7 = p[((unsigned)v1.w) >> CSH];
        atomicAdd(&sv[v0.x & (CN - 1)], p0);
        atomicAdd(&sv[v0.y & (CN - 1)], p1);
        atomicAdd(&sv[v0.z & (CN - 1)], p2);
        atomicAdd(&sv[v0.w & (CN - 1)], p3);
        atomicAdd(&sv[v1.x & (CN - 1)], p4);
        atomicAdd(&sv[v1.y & (CN - 1)], p5);
        atomicAdd(&sv[v1.z & (CN - 1)], p6);
        atomicAdd(&sv[v1.w & (CN - 1)], p7);
    }
    for (int e = a0 + 8 * nb + (int)threadIdx.x; e < e1; e += ATPB) {
        int v = packed[e];
        atomicAdd(&sv[v & (CN - 1)], p[((unsigned)v) >> CSH]);
    }
    __syncthreads();
    for (int i = threadIdx.x; i < nn; i += ATPB) {
        int node = node0 + i;
        float d = dis[node];
        float a = d * (sv[i] + p[node]);   // + self-loop
        float g0 = 0.0f, g1 = 0.0f;
#pragma unroll
        for (int q = 0; q < 16; ++q) {
            float h = fmaxf(W1[q] * a + b1[q], 0.0f);
            g0 += h * W2[2 * q];
            g1 += h * W2[2 * q + 1];
        }
        gp[node] = __float22half2_rn(make_float2(g0 * d, g1 * d));
    }
}

// ---------- packed fixed-point addend from half2 gather ----------
__device__ __forceinline__ unsigned long long fx_pack(const __half2 h) {
    float2 g = __half22float2(h);
    float gx = fminf(fmaxf(g.x, -15.9f), 15.9f);
    float gy = fminf(fmaxf(g.y, -15.9f), 15.9f);
    unsigned int ax = FXB + (unsigned int)__float2int_rn(gx * FXS);
    unsigned int ay = FXB + (unsigned int)__float2int_rn(gy * FXS);
    return ((unsigned long long)ay << 32) + (unsigned long long)ax;
}

// ---------- fused aggregation (1 u64 LDS atomic/edge) + bias -> out ----------
__global__ __launch_bounds__(ATPB) void k_o1(
    const int* __restrict__ packed, const int* __restrict__ bbase,
    const __half2* __restrict__ gp, const float* __restrict__ dis,
    const int* __restrict__ degArr,
    const float* __restrict__ b2, float* __restrict__ out, int n)
{
    __shared__ unsigned long long osum[CN];  // 8 KB
    int k = blockIdx.x;
    int node0 = k << CSH;
    int nn = min(CN, n - node0);
    for (int i = threadIdx.x; i < CN; i += ATPB) osum[i] = 0ULL;
    __syncthreads();
    int e0 = bbase[k], e1 = bbase[k + 1];
    int a0 = min((e0 + 3) & ~3, e1);
    int nb = (e1 - a0) >> 3;
    for (int e = e0 + (int)threadIdx.x; e < a0; e += ATPB) {
        int v = packed[e];
        atomicAdd(&osum[v & (CN - 1)], fx_pack(gp[((unsigned)v) >> CSH]));
    }
    const int4* pk4 = (const int4*)packed;
    int b4 = a0 >> 2;
    for (int g = threadIdx.x; g < nb; g += ATPB) {
        int4 v0 = pk4[b4 + 2 * g];
        int4 v1 = pk4[b4 + 2 * g + 1];
        unsigned long long a0p = fx_pack(gp[((unsigned)v0.x) >> CSH]);
        unsigned long long a1p = fx_pack(gp[((unsigned)v0.y) >> CSH]);
        unsigned long long a2p = fx_pack(gp[((unsigned)v0.z) >> CSH]);
        unsigned long long a3p = fx_pack(gp[((unsigned)v0.w) >> CSH]);
        unsigned long long a4p = fx_pack(gp[((unsigned)v1.x) >> CSH]);
        unsigned long long a5p = fx_pack(gp[((unsigned)v1.y) >> CSH]);
        unsigned long long a6p = fx_pack(gp[((unsigned)v1.z) >> CSH]);
        unsigned long long a7p = fx_pack(gp[((unsigned)v1.w) >> CSH]);
        atomicAdd(&osum[v0.x & (CN - 1)], a0p);
        atomicAdd(&osum[v0.y & (CN - 1)], a1p);
        atomicAdd(&osum[v0.z & (CN - 1)], a2p);
        atomicAdd(&osum[v0.w & (CN - 1)], a3p);
        atomicAdd(&osum[v1.x & (CN - 1)], a4p);
        atomicAdd(&osum[v1.y & (CN - 1)], a5p);
        atomicAdd(&osum[v1.z & (CN - 1)], a6p);
        atomicAdd(&osum[v1.w & (CN - 1)], a7p);
    }
    for (int e = a0 + 8 * nb + (int)threadIdx.x; e < e1; e += ATPB) {
        int v = packed[e];
        atomicAdd(&osum[v & (CN - 1)], fx_pack(gp[((unsigned)v) >> CSH]));
    }
    __syncthreads();
    float b20 = b2[0], b21 = b2[1];
    float2* out2 = (float2*)out;
    for (int i = threadIdx.x; i < nn; i += ATPB) {
        int node = node0 + i;
        float d = dis[node];
        unsigned long long sum = osum[i];
        unsigned int lo = (unsigned int)sum;
        unsigned int hi = (unsigned int)(sum >> 32);
        long long cb = (long long)degArr[node] * (long long)FXB;
        float sx = (float)((long long)lo - cb) * FXSI;
        float sy = (float)((long long)hi - cb) * FXSI;
        float2 gs = __half22float2(gp[node]);
        out2[node] = make_float2(d * (sx + gs.x) + b20, d * (sy + gs.y) + b21);
    }
}

// ---------- R1 fallback ----------
__global__ void f_init_deg(float* __restrict__ deg, int n) {
    int i = blockIdx.x * blockDim.x + threadIdx.x;
    if (i < n) deg[i] = 1.0f;
}
__global__ void f_deg(const int* __restrict__ col, float* __restrict__ deg, int ne) {
    int tid = blockIdx.x * blockDim.x + threadIdx.x;
    int stride = gridDim.x * blockDim.x;
    for (int e = tid; e < ne; e += stride) atomicAdd(&deg[col[e]], 1.0f);
}
__global__ void f_dis(const float* __restrict__ x, float* __restrict__ deg_dis,
                      float* __restrict__ p, float* __restrict__ s, int n) {
    int i = blockIdx.x * blockDim.x + threadIdx.x;
    if (i >= n) return;
    float dis = rsqrtf(deg_dis[i]);
    deg_dis[i] = dis;
    float pv = x[i] * dis;
    p[i] = pv;
    s[i] = pv;
}
__global__ void f_scatter1(const int* __restrict__ row, const int* __restrict__ col,
                           const float* __restrict__ p, float* __restrict__ s, int ne) {
    int tid = blockIdx.x * blockDim.x + threadIdx.x;
    int stride = gridDim.x * blockDim.x;
    for (int e = tid; e < ne; e += stride) atomicAdd(&s[col[e]], p[row[e]]);
}
__global__ void f_node(const float* __restrict__ dis, const float* __restrict__ s,
                       const float* __restrict__ W1, const float* __restrict__ b1,
                       const float* __restrict__ W2,
                       float* __restrict__ gp, float* __restrict__ out, int n) {
    int i = blockIdx.x * blockDim.x + threadIdx.x;
    if (i >= n) return;
    float d = dis[i];
    float a = d * s[i];
    float g0 = 0.0f, g1 = 0.0f;
#pragma unroll
    for (int q = 0; q < 16; ++q) {
        float h = fmaxf(W1[q] * a + b1[q], 0.0f);
        g0 += h * W2[2 * q];
        g1 += h * W2[2 * q + 1];
    }
    ((float2*)gp)[i] = make_float2(g0 * d, g1 * d);
    ((float2*)out)[i] = make_float2(g0 * d, g1 * d);
}
__global__ void f_scatter2(const int* __restrict__ row, const int* __restrict__ col,
                           const float* __restrict__ gp, float* __restrict__ out, int ne) {
    int tid = blockIdx.x * blockDim.x + threadIdx.x;
    int stride = gridDim.x * blockDim.x;
    const float2* gp2 = (const float2*)gp;
    for (int e = tid; e < ne; e += stride) {
        float2 g = gp2[row[e]];
        atomicAdd(&out[2 * col[e]], g.x);
        atomicAdd(&out[2 * col[e] + 1], g.y);
    }
}
__global__ void f_final(const float* __restrict__ dis, const float* __restrict__ b2,
                        float* __restrict__ out, int n) {
    int i = blockIdx.x * blockDim.x + threadIdx.x;
    if (i >= n) return;
    float d = dis[i];
    float2* out2 = (float2*)out;
    float2 t = out2[i];
    out2[i] = make_float2(d * t.x + b2[0], d * t.y + b2[1]);
}

// ---------------- launch ----------------

extern "C" void kernel_launch(void* const* d_in, const int* in_sizes, int n_in,
                              void* d_out, int out_size, void* d_ws, size_t ws_size,
                              hipStream_t stream) {
    const float* x = (const float*)d_in[0];
    const int* edge_index = (const int*)d_in[1];
    const float* W1 = (const float*)d_in[2];
    const float* b1 = (const float*)d_in[3];
    const float* W2 = (const float*)d_in[4];
    const float* b2 = (const float*)d_in[5];
    float* out = (float*)d_out;

    int n = in_sizes[0];
    int ne = in_sizes[1] / 2;
    const int* row = edge_index;
    const int* col = edge_index + ne;

    int ne4 = ((ne & 3) == 0) ? (ne >> 2) : 0;
    int nodeBlocks = (n + 255) / 256;

    // ---------- main path: R13 skeleton + keyed k_part (no binary search) ----------
    {
        int K = (n + CN - 1) >> CSH;
        size_t off = 0;
        auto alloc = [&](size_t bytes) -> char* {
            char* ptr = (char*)d_ws + off;
            off += (bytes + 255) & ~(size_t)255;
            return ptr;
        };
        int* totals = (int*)alloc((size_t)K * sizeof(int));
        int* bbase  = (int*)alloc((size_t)(K + 1) * sizeof(int));
        int* cursor = (int*)alloc((size_t)K * sizeof(int));
        int* packed = (int*)alloc((size_t)ne * sizeof(int));
        float* dis  = (float*)alloc((size_t)n * sizeof(float));
        float* p    = (float*)alloc((size_t)n * sizeof(float));
        int* degArr = (int*)alloc((size_t)n * sizeof(int));
        __half2* gp = (__half2*)alloc((size_t)n * sizeof(__half2));

        bool ok = (off <= ws_size) && (K >= 1) && (K <= KMAX) && (ne > 0);
        if (ok) {
            int partBlocks = (ne + PTILE - 1) / PTILE;
            k_zero<<<(K + 255) / 256, 256, 0, stream>>>(totals, K);
            k_count<<<1024, 256, 0, stream>>>(col, ne, ne4, totals, K);
            k_scan<<<1, 64, 0, stream>>>(totals, bbase, cursor, K);
            k_part<<<partBlocks, PTPB, 0, stream>>>(row, col, ne, cursor, packed, K);
            k_deg1<<<K, ATPB, 0, stream>>>(x, packed, bbase, dis, p, degArr, n);
            k_s1<<<K, ATPB, 0, stream>>>(packed, bbase, p, dis, W1, b1, W2, gp, n);
            k_o1<<<K, ATPB, 0, stream>>>(packed, bbase, gp, dis, degArr, b2, out, n);
            return;
        }
    }

    // ---------- R1 fallback ----------
    {
        float* ws = (float*)d_ws;
        float* deg_dis = ws;
        float* pp = ws + n;
        float* ss = ws + 2 * (size_t)n;
        float* gpp = ws + 3 * (size_t)n;
        int edgeBlocks = 4096;
        f_init_deg<<<nodeBlocks, 256, 0, stream>>>(deg_dis, n);
        f_deg<<<edgeBlocks, 256, 0, stream>>>(col, deg_dis, ne);
        f_dis<<<nodeBlocks, 256, 0, stream>>>(x, deg_dis, pp, ss, n);
        f_scatter1<<<edgeBlocks, 256, 0, stream>>>(row, col, pp, ss, ne);
        f_node<<<nodeBlocks, 256, 0, stream>>>(deg_dis, ss, W1, b1, W2, gpp, out, n);
        f_scatter2<<<edgeBlocks, 256, 0, stream>>>(row, col, gpp, out, ne);
        f_final<<<nodeBlocks, 256, 0, stream>>>(deg_dis, b2, out, n);
    }
}

// Round 15
// 312.753 us; speedup vs baseline: 1.0904x; 1.0904x over previous
//
#include <hip/hip_runtime.h>
#include <hip/hip_fp16.h>

// GCN 2-layer collapsed (x is [N,1] => layer 1 is rank-1):
//   out[c] = dis[c]*(sum_{r->c} gp[r] + gp[c]) + b2,  gp[r] = (relu(W1*a[r]+b1)@W2)*dis[r]
//   a[r]   = dis[r]*(sum_{r'->r} p[r'] + p[r]),       p[r']=x[r']*dis[r'], dis=1/sqrt(deg+1)
//
// Empirical laws (R1-R14): global atomics 20G/s; scattered 4B global stores ~10x
// write-through (only run-coalesced writes); aggregation passes are LDS-ATOMIC-PIPE
// bound (~55us/lane-op/edge + gather surcharge), invariant to occupancy/sorting/
// caching/preload/ILP. R13: u64-packed o-pass -> 325us. R14: binary-search removal
// helped VALU (40->11%) but 4096-tile write-amp regressed (+15us).
// R15: keyed search-free k_part at PTILE=8192 via u8 key + monotone-crossing trick
// (key nondecreasing along tile; K<512 so high bit flips once, at s_start[256]).

#define KMAX  512
#define PTPB  512
#define PU    16
#define PTILE (PTPB * PU)    // 8192

#define CSH   10
#define CN    1024
#define ATPB  256

#define FXS   131072.0f          // 2^17
#define FXSI  (1.0f / 131072.0f)
#define FXB   (1u << 21)

// ---------- zero ----------
__global__ void k_zero(int* __restrict__ a, int m) {
    int i = blockIdx.x * blockDim.x + threadIdx.x;
    if (i < m) a[i] = 0;
}

// ---------- chunk histogram ----------
__global__ void k_count(const int* __restrict__ col, int ne, int ne4,
                        int* __restrict__ totals, int K) {
    __shared__ int cnt[KMAX];
    for (int i = threadIdx.x; i < K; i += blockDim.x) cnt[i] = 0;
    __syncthreads();
    int tid = blockIdx.x * blockDim.x + threadIdx.x;
    int stride = gridDim.x * blockDim.x;
    const int4* col4 = (const int4*)col;
    for (int e = tid; e < ne4; e += stride) {
        int4 cc = col4[e];
        atomicAdd(&cnt[cc.x >> CSH], 1);
        atomicAdd(&cnt[cc.y >> CSH], 1);
        atomicAdd(&cnt[cc.z >> CSH], 1);
        atomicAdd(&cnt[cc.w >> CSH], 1);
    }
    for (int e = (ne4 << 2) + tid; e < ne; e += stride)
        atomicAdd(&cnt[col[e] >> CSH], 1);
    __syncthreads();
    for (int i = threadIdx.x; i < K; i += blockDim.x)
        if (cnt[i]) atomicAdd(&totals[i], cnt[i]);
}

// ---------- serial scan (K<=512) ----------
__global__ void k_scan(const int* __restrict__ totals, int* __restrict__ bbase,
                       int* __restrict__ cursor, int K) {
    if (threadIdx.x == 0 && blockIdx.x == 0) {
        int run = 0;
        for (int k = 0; k < K; ++k) { bbase[k] = run; cursor[k] = run; run += totals[k]; }
        bbase[K] = run;
    }
}

// ---------- tile-local LDS counting sort partition (key = col>>CSH) ----------
// R15: u8 key + crossing trick; output = s_off[key] + i (search-free, 8192 tile)
__global__ __launch_bounds__(PTPB) void k_part(
    const int* __restrict__ row, const int* __restrict__ col, int ne,
    int* __restrict__ cursor, int* __restrict__ packed, int K)
{
    __shared__ int s_cnt[KMAX];
    __shared__ int s_start[KMAX + 1];
    __shared__ int s_cur[KMAX];
    __shared__ int s_off[KMAX];
    __shared__ int s_sorted[PTILE];             // 32 KB
    __shared__ unsigned char s_key8[PTILE];     // 8 KB
    __shared__ int s_cross;

    int tb = blockIdx.x * PTILE;
    int tilecount = ne - tb;
    if (tilecount > PTILE) tilecount = PTILE;

    for (int i = threadIdx.x; i < K; i += PTPB) s_cnt[i] = 0;
    __syncthreads();

    int r[PU], c[PU];
    const int4* row4 = (const int4*)row;
    const int4* col4 = (const int4*)col;
    int tb4 = tb >> 2;
#pragma unroll
    for (int j = 0; j < PU / 4; ++j) {
        int g4 = tb4 + j * PTPB + threadIdx.x;
        int e = g4 << 2;
        if (e + 3 < ne) {
            int4 rr = row4[g4];
            int4 cc = col4[g4];
            r[4 * j + 0] = rr.x; r[4 * j + 1] = rr.y; r[4 * j + 2] = rr.z; r[4 * j + 3] = rr.w;
            c[4 * j + 0] = cc.x; c[4 * j + 1] = cc.y; c[4 * j + 2] = cc.z; c[4 * j + 3] = cc.w;
        } else {
#pragma unroll
            for (int q = 0; q < 4; ++q) {
                int e2 = e + q;
                if (e2 < ne) { r[4 * j + q] = row[e2]; c[4 * j + q] = col[e2]; }
                else { r[4 * j + q] = 0; c[4 * j + q] = -1; }
            }
        }
    }
#pragma unroll
    for (int j = 0; j < PU; ++j)
        if (c[j] >= 0) atomicAdd(&s_cnt[c[j] >> CSH], 1);
    __syncthreads();

    if (threadIdx.x == 0) {
        int run = 0;
        for (int k = 0; k < K; ++k) { s_start[k] = run; run += s_cnt[k]; }
        s_start[K] = run;
        s_cross = (K > 256) ? s_start[256] : (PTILE + 1);
    }
    __syncthreads();
    if ((int)threadIdx.x < K) {
        int n0 = s_cnt[threadIdx.x];
        int gbase = n0 ? atomicAdd(&cursor[threadIdx.x], n0) : 0;
        s_off[threadIdx.x] = gbase - s_start[threadIdx.x];
        s_cur[threadIdx.x] = s_start[threadIdx.x];
    }
    __syncthreads();

#pragma unroll
    for (int j = 0; j < PU; ++j) {
        if (c[j] >= 0) {
            int ck = c[j] >> CSH;
            int pos = atomicAdd(&s_cur[ck], 1);
            s_sorted[pos] = (r[j] << CSH) | (c[j] & (CN - 1));
            s_key8[pos] = (unsigned char)ck;
        }
    }
    __syncthreads();

    int cross = s_cross;
    for (int i = threadIdx.x; i < tilecount; i += PTPB) {
        int key = (int)s_key8[i] + ((i >= cross) ? 256 : 0);
        packed[s_off[key] + i] = s_sorted[i];
    }
}

// ---------- fused degree -> dis, p, degArr (one block per chunk) ----------
__global__ __launch_bounds__(ATPB) void k_deg1(
    const float* __restrict__ x, const int* __restrict__ packed,
    const int* __restrict__ bbase, float* __restrict__ dis, float* __restrict__ p,
    int* __restrict__ degArr, int n)
{
    __shared__ int cnt[CN];
    int k = blockIdx.x;
    int node0 = k << CSH;
    int nn = min(CN, n - node0);
    for (int i = threadIdx.x; i < CN; i += ATPB) cnt[i] = 0;
    __syncthreads();
    int e0 = bbase[k], e1 = bbase[k + 1];
    int a0 = min((e0 + 3) & ~3, e1);
    int nb = (e1 - a0) >> 3;   // 8-edge groups
    for (int e = e0 + (int)threadIdx.x; e < a0; e += ATPB)
        atomicAdd(&cnt[packed[e] & (CN - 1)], 1);
    const int4* pk4 = (const int4*)packed;
    int b4 = a0 >> 2;
    for (int g = threadIdx.x; g < nb; g += ATPB) {
        int4 v0 = pk4[b4 + 2 * g];
        int4 v1 = pk4[b4 + 2 * g + 1];
        atomicAdd(&cnt[v0.x & (CN - 1)], 1);
        atomicAdd(&cnt[v0.y & (CN - 1)], 1);
        atomicAdd(&cnt[v0.z & (CN - 1)], 1);
        atomicAdd(&cnt[v0.w & (CN - 1)], 1);
        atomicAdd(&cnt[v1.x & (CN - 1)], 1);
        atomicAdd(&cnt[v1.y & (CN - 1)], 1);
        atomicAdd(&cnt[v1.z & (CN - 1)], 1);
        atomicAdd(&cnt[v1.w & (CN - 1)], 1);
    }
    for (int e = a0 + 8 * nb + (int)threadIdx.x; e < e1; e += ATPB)
        atomicAdd(&cnt[packed[e] & (CN - 1)], 1);
    __syncthreads();
    for (int i = threadIdx.x; i < nn; i += ATPB) {
        int c0 = cnt[i];
        float ds = rsqrtf(1.0f + (float)c0);
        dis[node0 + i] = ds;
        p[node0 + i] = x[node0 + i] * ds;
        degArr[node0 + i] = c0;
    }
}

// ---------- fused scalar aggregation + MLP -> gp (__half2) ----------
__global__ __launch_bounds__(ATPB) void k_s1(
    const int* __restrict__ packed, const int* __restrict__ bbase,
    const float* __restrict__ p, const float* __restrict__ dis,
    const float* __restrict__ W1, const float* __restrict__ b1,
    const float* __restrict__ W2, __half2* __restrict__ gp, int n)
{
    __shared__ float sv[CN];
    int k = blockIdx.x;
    int node0 = k << CSH;
    int nn = min(CN, n - node0);
    for (int i = threadIdx.x; i < CN; i += ATPB) sv[i] = 0.0f;
    __syncthreads();
    int e0 = bbase[k], e1 = bbase[k + 1];
    int a0 = min((e0 + 3) & ~3, e1);
    int nb = (e1 - a0) >> 3;
    for (int e = e0 + (int)threadIdx.x; e < a0; e += ATPB) {
        int v = packed[e];
        atomicAdd(&sv[v & (CN - 1)], p[((unsigned)v) >> CSH]);
    }
    const int4* pk4 = (const int4*)packed;
    int b4 = a0 >> 2;
    for (int g = threadIdx.x; g < nb; g += ATPB) {
        int4 v0 = pk4[b4 + 2 * g];
        int4 v1 = pk4[b4 + 2 * g + 1];
        float p0 = p[((unsigned)v0.x) >> CSH];
        float p1 = p[((unsigned)v0.y) >> CSH];
        float p2 = p[((unsigned)v0.z) >> CSH];
        float p3 = p[((unsigned)v0.w) >> CSH];
        float p4 = p[((unsigned)v1.x) >> CSH];
        float p5 = p[((unsigned)v1.y) >> CSH];
        float p6 = p[((unsigned)v1.z) >> CSH];
        float p7 = p[((unsigned)v1.w) >> CSH];
        atomicAdd(&sv[v0.x & (CN - 1)], p0);
        atomicAdd(&sv[v0.y & (CN - 1)], p1);
        atomicAdd(&sv[v0.z & (CN - 1)], p2);
        atomicAdd(&sv[v0.w & (CN - 1)], p3);
        atomicAdd(&sv[v1.x & (CN - 1)], p4);
        atomicAdd(&sv[v1.y & (CN - 1)], p5);
        atomicAdd(&sv[v1.z & (CN - 1)], p6);
        atomicAdd(&sv[v1.w & (CN - 1)], p7);
    }
    for (int e = a0 + 8 * nb + (int)threadIdx.x; e < e1; e += ATPB) {
        int v = packed[e];
        atomicAdd(&sv[v & (CN - 1)], p[((unsigned)v) >> CSH]);
    }
    __syncthreads();
    for (int i = threadIdx.x; i < nn; i += ATPB) {
        int node = node0 + i;
        float d = dis[node];
        float a = d * (sv[i] + p[node]);   // + self-loop
        float g0 = 0.0f, g1 = 0.0f;
#pragma unroll
        for (int q = 0; q < 16; ++q) {
            float h = fmaxf(W1[q] * a + b1[q], 0.0f);
            g0 += h * W2[2 * q];
            g1 += h * W2[2 * q + 1];
        }
        gp[node] = __float22half2_rn(make_float2(g0 * d, g1 * d));
    }
}

// ---------- packed fixed-point addend from half2 gather ----------
__device__ __forceinline__ unsigned long long fx_pack(const __half2 h) {
    float2 g = __half22float2(h);
    float gx = fminf(fmaxf(g.x, -15.9f), 15.9f);
    float gy = fminf(fmaxf(g.y, -15.9f), 15.9f);
    unsigned int ax = FXB + (unsigned int)__float2int_rn(gx * FXS);
    unsigned int ay = FXB + (unsigned int)__float2int_rn(gy * FXS);
    return ((unsigned long long)ay << 32) + (unsigned long long)ax;
}

// ---------- fused aggregation (1 u64 LDS atomic/edge) + bias -> out ----------
__global__ __launch_bounds__(ATPB) void k_o1(
    const int* __restrict__ packed, const int* __restrict__ bbase,
    const __half2* __restrict__ gp, const float* __restrict__ dis,
    const int* __restrict__ degArr,
    const float* __restrict__ b2, float* __restrict__ out, int n)
{
    __shared__ unsigned long long osum[CN];  // 8 KB
    int k = blockIdx.x;
    int node0 = k << CSH;
    int nn = min(CN, n - node0);
    for (int i = threadIdx.x; i < CN; i += ATPB) osum[i] = 0ULL;
    __syncthreads();
    int e0 = bbase[k], e1 = bbase[k + 1];
    int a0 = min((e0 + 3) & ~3, e1);
    int nb = (e1 - a0) >> 3;
    for (int e = e0 + (int)threadIdx.x; e < a0; e += ATPB) {
        int v = packed[e];
        atomicAdd(&osum[v & (CN - 1)], fx_pack(gp[((unsigned)v) >> CSH]));
    }
    const int4* pk4 = (const int4*)packed;
    int b4 = a0 >> 2;
    for (int g = threadIdx.x; g < nb; g += ATPB) {
        int4 v0 = pk4[b4 + 2 * g];
        int4 v1 = pk4[b4 + 2 * g + 1];
        unsigned long long a0p = fx_pack(gp[((unsigned)v0.x) >> CSH]);
        unsigned long long a1p = fx_pack(gp[((unsigned)v0.y) >> CSH]);
        unsigned long long a2p = fx_pack(gp[((unsigned)v0.z) >> CSH]);
        unsigned long long a3p = fx_pack(gp[((unsigned)v0.w) >> CSH]);
        unsigned long long a4p = fx_pack(gp[((unsigned)v1.x) >> CSH]);
        unsigned long long a5p = fx_pack(gp[((unsigned)v1.y) >> CSH]);
        unsigned long long a6p = fx_pack(gp[((unsigned)v1.z) >> CSH]);
        unsigned long long a7p = fx_pack(gp[((unsigned)v1.w) >> CSH]);
        atomicAdd(&osum[v0.x & (CN - 1)], a0p);
        atomicAdd(&osum[v0.y & (CN - 1)], a1p);
        atomicAdd(&osum[v0.z & (CN - 1)], a2p);
        atomicAdd(&osum[v0.w & (CN - 1)], a3p);
        atomicAdd(&osum[v1.x & (CN - 1)], a4p);
        atomicAdd(&osum[v1.y & (CN - 1)], a5p);
        atomicAdd(&osum[v1.z & (CN - 1)], a6p);
        atomicAdd(&osum[v1.w & (CN - 1)], a7p);
    }
    for (int e = a0 + 8 * nb + (int)threadIdx.x; e < e1; e += ATPB) {
        int v = packed[e];
        atomicAdd(&osum[v & (CN - 1)], fx_pack(gp[((unsigned)v) >> CSH]));
    }
    __syncthreads();
    float b20 = b2[0], b21 = b2[1];
    float2* out2 = (float2*)out;
    for (int i = threadIdx.x; i < nn; i += ATPB) {
        int node = node0 + i;
        float d = dis[node];
        unsigned long long sum = osum[i];
        unsigned int lo = (unsigned int)sum;
        unsigned int hi = (unsigned int)(sum >> 32);
        long long cb = (long long)degArr[node] * (long long)FXB;
        float sx = (float)((long long)lo - cb) * FXSI;
        float sy = (float)((long long)hi - cb) * FXSI;
        float2 gs = __half22float2(gp[node]);
        out2[node] = make_float2(d * (sx + gs.x) + b20, d * (sy + gs.y) + b21);
    }
}

// ---------- R1 fallback ----------
__global__ void f_init_deg(float* __restrict__ deg, int n) {
    int i = blockIdx.x * blockDim.x + threadIdx.x;
    if (i < n) deg[i] = 1.0f;
}
__global__ void f_deg(const int* __restrict__ col, float* __restrict__ deg, int ne) {
    int tid = blockIdx.x * blockDim.x + threadIdx.x;
    int stride = gridDim.x * blockDim.x;
    for (int e = tid; e < ne; e += stride) atomicAdd(&deg[col[e]], 1.0f);
}
__global__ void f_dis(const float* __restrict__ x, float* __restrict__ deg_dis,
                      float* __restrict__ p, float* __restrict__ s, int n) {
    int i = blockIdx.x * blockDim.x + threadIdx.x;
    if (i >= n) return;
    float dis = rsqrtf(deg_dis[i]);
    deg_dis[i] = dis;
    float pv = x[i] * dis;
    p[i] = pv;
    s[i] = pv;
}
__global__ void f_scatter1(const int* __restrict__ row, const int* __restrict__ col,
                           const float* __restrict__ p, float* __restrict__ s, int ne) {
    int tid = blockIdx.x * blockDim.x + threadIdx.x;
    int stride = gridDim.x * blockDim.x;
    for (int e = tid; e < ne; e += stride) atomicAdd(&s[col[e]], p[row[e]]);
}
__global__ void f_node(const float* __restrict__ dis, const float* __restrict__ s,
                       const float* __restrict__ W1, const float* __restrict__ b1,
                       const float* __restrict__ W2,
                       float* __restrict__ gp, float* __restrict__ out, int n) {
    int i = blockIdx.x * blockDim.x + threadIdx.x;
    if (i >= n) return;
    float d = dis[i];
    float a = d * s[i];
    float g0 = 0.0f, g1 = 0.0f;
#pragma unroll
    for (int q = 0; q < 16; ++q) {
        float h = fmaxf(W1[q] * a + b1[q], 0.0f);
        g0 += h * W2[2 * q];
        g1 += h * W2[2 * q + 1];
    }
    ((float2*)gp)[i] = make_float2(g0 * d, g1 * d);
    ((float2*)out)[i] = make_float2(g0 * d, g1 * d);
}
__global__ void f_scatter2(const int* __restrict__ row, const int* __restrict__ col,
                           const float* __restrict__ gp, float* __restrict__ out, int ne) {
    int tid = blockIdx.x * blockDim.x + threadIdx.x;
    int stride = gridDim.x * blockDim.x;
    const float2* gp2 = (const float2*)gp;
    for (int e = tid; e < ne; e += stride) {
        float2 g = gp2[row[e]];
        atomicAdd(&out[2 * col[e]], g.x);
        atomicAdd(&out[2 * col[e] + 1], g.y);
    }
}
__global__ void f_final(const float* __restrict__ dis, const float* __restrict__ b2,
                        float* __restrict__ out, int n) {
    int i = blockIdx.x * blockDim.x + threadIdx.x;
    if (i >= n) return;
    float d = dis[i];
    float2* out2 = (float2*)out;
    float2 t = out2[i];
    out2[i] = make_float2(d * t.x + b2[0], d * t.y + b2[1]);
}

// ---------------- launch ----------------

extern "C" void kernel_launch(void* const* d_in, const int* in_sizes, int n_in,
                              void* d_out, int out_size, void* d_ws, size_t ws_size,
                              hipStream_t stream) {
    const float* x = (const float*)d_in[0];
    const int* edge_index = (const int*)d_in[1];
    const float* W1 = (const float*)d_in[2];
    const float* b1 = (const float*)d_in[3];
    const float* W2 = (const float*)d_in[4];
    const float* b2 = (const float*)d_in[5];
    float* out = (float*)d_out;

    int n = in_sizes[0];
    int ne = in_sizes[1] / 2;
    const int* row = edge_index;
    const int* col = edge_index + ne;

    int ne4 = ((ne & 3) == 0) ? (ne >> 2) : 0;
    int nodeBlocks = (n + 255) / 256;

    // ---------- main path: R13 skeleton + u8-keyed search-free k_part ----------
    {
        int K = (n + CN - 1) >> CSH;
        size_t off = 0;
        auto alloc = [&](size_t bytes) -> char* {
            char* ptr = (char*)d_ws + off;
            off += (bytes + 255) & ~(size_t)255;
            return ptr;
        };
        int* totals = (int*)alloc((size_t)K * sizeof(int));
        int* bbase  = (int*)alloc((size_t)(K + 1) * sizeof(int));
        int* cursor = (int*)alloc((size_t)K * sizeof(int));
        int* packed = (int*)alloc((size_t)ne * sizeof(int));
        float* dis  = (float*)alloc((size_t)n * sizeof(float));
        float* p    = (float*)alloc((size_t)n * sizeof(float));
        int* degArr = (int*)alloc((size_t)n * sizeof(int));
        __half2* gp = (__half2*)alloc((size_t)n * sizeof(__half2));

        bool ok = (off <= ws_size) && (K >= 1) && (K <= KMAX) && (ne > 0);
        if (ok) {
            int partBlocks = (ne + PTILE - 1) / PTILE;
            k_zero<<<(K + 255) / 256, 256, 0, stream>>>(totals, K);
            k_count<<<1024, 256, 0, stream>>>(col, ne, ne4, totals, K);
            k_scan<<<1, 64, 0, stream>>>(totals, bbase, cursor, K);
            k_part<<<partBlocks, PTPB, 0, stream>>>(row, col, ne, cursor, packed, K);
            k_deg1<<<K, ATPB, 0, stream>>>(x, packed, bbase, dis, p, degArr, n);
            k_s1<<<K, ATPB, 0, stream>>>(packed, bbase, p, dis, W1, b1, W2, gp, n);
            k_o1<<<K, ATPB, 0, stream>>>(packed, bbase, gp, dis, degArr, b2, out, n);
            return;
        }
    }

    // ---------- R1 fallback ----------
    {
        float* ws = (float*)d_ws;
        float* deg_dis = ws;
        float* pp = ws + n;
        float* ss = ws + 2 * (size_t)n;
        float* gpp = ws + 3 * (size_t)n;
        int edgeBlocks = 4096;
        f_init_deg<<<nodeBlocks, 256, 0, stream>>>(deg_dis, n);
        f_deg<<<edgeBlocks, 256, 0, stream>>>(col, deg_dis, ne);
        f_dis<<<nodeBlocks, 256, 0, stream>>>(x, deg_dis, pp, ss, n);
        f_scatter1<<<edgeBlocks, 256, 0, stream>>>(row, col, pp, ss, ne);
        f_node<<<nodeBlocks, 256, 0, stream>>>(deg_dis, ss, W1, b1, W2, gpp, out, n);
        f_scatter2<<<edgeBlocks, 256, 0, stream>>>(row, col, gpp, out, ne);
        f_final<<<nodeBlocks, 256, 0, stream>>>(deg_dis, b2, out, n);
    }
}